// Round 1
// baseline (9628.728 us; speedup 1.0000x reference)
//
#include <hip/hip_runtime.h>

typedef unsigned short u16;
typedef __attribute__((ext_vector_type(8))) short short8;
typedef __attribute__((ext_vector_type(4))) float f32x4;

#define DEVI __device__ __forceinline__

DEVI u16 f2bf(float f){ union{float f;unsigned u;} v; v.f=f; unsigned r=v.u+0x7FFFu+((v.u>>16)&1u); return (u16)(r>>16); }
DEVI float bf2f(u16 h){ union{unsigned u;float f;} v; v.u=((unsigned)h)<<16; return v.f; }
DEVI float sigm(float x){ return 1.f/(1.f+__expf(-x)); }
DEVI f32x4 mfma16(short8 a, short8 b, f32x4 c){ return __builtin_amdgcn_mfma_f32_16x16x32_bf16(a,b,c,0,0,0); }

// 64(M)x64(N) tile GEMM core: C += A[64xK] * W[NxK]^T, 4 waves, wave w owns cols [w*16,w*16+16)
// caller pre-offsets A to row m0, Wn to row (n0 + wave*16)
DEVI void mm64(const u16* __restrict__ A, long lda, const u16* __restrict__ Wn, long ldw,
               int K, f32x4 acc[4])
{
  int lane = threadIdx.x & 63;
  int r16 = lane & 15, kg = lane >> 4;
  const u16* ap = A + (long)r16*lda + kg*8;
  const u16* wp = Wn + (long)r16*ldw + kg*8;
  for (int k=0; k<K; k+=32){
    short8 b  = *reinterpret_cast<const short8*>(wp + k);
    short8 a0 = *reinterpret_cast<const short8*>(ap + k);
    short8 a1 = *reinterpret_cast<const short8*>(ap + 16*lda + k);
    short8 a2 = *reinterpret_cast<const short8*>(ap + 32*lda + k);
    short8 a3 = *reinterpret_cast<const short8*>(ap + 48*lda + k);
    acc[0]=mfma16(a0,b,acc[0]); acc[1]=mfma16(a1,b,acc[1]);
    acc[2]=mfma16(a2,b,acc[2]); acc[3]=mfma16(a3,b,acc[3]);
  }
}

// ---------------- generic GEMM: C = A @ W^T + bias ----------------
template<int OBF>
__global__ __launch_bounds__(256) void rbn_gemm(const u16* __restrict__ A, long lda,
    const u16* __restrict__ W, long ldw, int K, const float* __restrict__ bias,
    void* __restrict__ C, long ldc, int nbN)
{
  int mb = blockIdx.x / nbN, nb = blockIdx.x % nbN;
  int lane = threadIdx.x & 63, wv = threadIdx.x >> 6;
  int r16 = lane & 15, kg = lane >> 4;
  f32x4 acc[4]; for (int i=0;i<4;i++) acc[i] = (f32x4){0.f,0.f,0.f,0.f};
  int n0 = nb*64 + wv*16;
  mm64(A + (long)mb*64*lda, lda, W + (long)n0*ldw, ldw, K, acc);
  int col = n0 + r16;
  float bv = bias ? bias[col] : 0.f;
  #pragma unroll
  for (int i=0;i<4;i++)
    #pragma unroll
    for (int r=0;r<4;r++){
      long row = (long)mb*64 + i*16 + kg*4 + r;
      float v = acc[i][r] + bv;
      if (OBF) ((u16*)C)[row*ldc+col] = f2bf(v);
      else     ((float*)C)[row*ldc+col] = v;
    }
}

// ---------------- misc small kernels ----------------
__global__ void rbn_cvt(const float* __restrict__ in, u16* __restrict__ out, int n){
  int i = blockIdx.x*256 + threadIdx.x; if (i < n) out[i] = f2bf(in[i]);
}
// in [R][C] fp32 -> out [C][R] bf16
__global__ void rbn_cvtT(const float* __restrict__ in, u16* __restrict__ out, int R, int C){
  int i = blockIdx.x*256 + threadIdx.x;
  if (i < R*C){ int c = i / R, r = i % R; out[i] = f2bf(in[(long)r*C + c]); }
}
// out[i] = sum_k W[i*ldk+k]*u[k] + add[i]
__global__ __launch_bounds__(256) void rbn_matvec(const float* __restrict__ W, long ldk, int K,
    const float* __restrict__ u, const float* __restrict__ add, float* __restrict__ out)
{
  int i = blockIdx.x;
  float p = 0.f;
  for (int k=threadIdx.x; k<K; k+=256) p += W[(long)i*ldk + k]*u[k];
  __shared__ float red[256];
  red[threadIdx.x] = p; __syncthreads();
  for (int w=128; w; w>>=1){ if (threadIdx.x<w) red[threadIdx.x]+=red[threadIdx.x+w]; __syncthreads(); }
  if (threadIdx.x==0) out[i] = red[0] + (add ? add[i] : 0.f);
}
// out[768][12] = wk(768x768) @ wst(768x12)
__global__ void rbn_wsmall(const float* __restrict__ wk, const float* __restrict__ wst, float* __restrict__ out){
  int i = blockIdx.x, j = threadIdx.x;
  if (j < 12){
    float s = 0.f;
    for (int k=0;k<768;k++) s += wk[(long)i*768+k]*wst[(long)k*12+j];
    out[i*12+j] = s;
  }
}
__global__ void rbn_zero(u16* bp, u16* h0, u16* h1, float* racc){
  int i = blockIdx.x*256 + threadIdx.x;
  if (i < 196608){ bp[i]=0; h0[i]=0; h1[i]=0; }
  if (i == 0) racc[0] = 0.f;
}
// visual (B,T,V) fp32 -> vis_tb [S][B][768] bf16  (row = t*256+b)
__global__ __launch_bounds__(256) void rbn_cvt_vis(const float* __restrict__ vis, u16* __restrict__ vt){
  int row = blockIdx.x; int t = row >> 8, b = row & 255;
  const float* src = vis + ((long)b*64 + t)*768;
  u16* dst = vt + (long)row*768;
  for (int v=threadIdx.x; v<768; v+=256) dst[v] = f2bf(src[v]);
}
// v1[t,b,h] = sum_s state[b,t,s]*Wsv[h,s] + beta[h]
__global__ __launch_bounds__(256) void rbn_v1(const float* __restrict__ state, const float* __restrict__ Wsv,
    const float* __restrict__ beta, u16* __restrict__ v1)
{
  long g = (long)blockIdx.x*256 + threadIdx.x;
  if (g >= (long)16128*768) return;
  int row = (int)(g/768), h = (int)(g%768);
  int t = row >> 8, b = row & 255;
  const float* st = state + ((long)b*64 + t)*12;
  float s = beta[h];
  #pragma unroll
  for (int k=0;k<12;k++) s += st[k]*Wsv[h*12+k];
  v1[g] = f2bf(s);
}
// k2-tile via GEMM + k1-tile via K=12, then s12 = SCALE * q2 . k{1,2}
__global__ __launch_bounds__(256) void rbn_s12(const u16* __restrict__ vis_tb, const u16* __restrict__ Wc_vk,
    const float* __restrict__ beta_vk, const float* __restrict__ W_sk, const float* __restrict__ beta_sk,
    const float* __restrict__ state, const u16* __restrict__ q2, float* __restrict__ s12)
{
  int mb = blockIdx.x/12, n = blockIdx.x%12;
  __shared__ float k2s[64*65];
  __shared__ float k1s[64*65];
  int lane = threadIdx.x & 63, wv = threadIdx.x >> 4 >> 2; // wv = tid>>6
  wv = threadIdx.x >> 6;
  int r16 = lane & 15, kg = lane >> 4;
  f32x4 acc[4]; for (int i=0;i<4;i++) acc[i] = (f32x4){0.f,0.f,0.f,0.f};
  int n0 = n*64 + wv*16;
  mm64(vis_tb + (long)mb*64*768, 768, Wc_vk + (long)n0*768, 768, 768, acc);
  #pragma unroll
  for (int i=0;i<4;i++)
    #pragma unroll
    for (int r=0;r<4;r++)
      k2s[(i*16+kg*4+r)*65 + wv*16 + r16] = acc[i][r] + beta_vk[n0 + r16];
  // k1
  {
    int rl = threadIdx.x >> 2, q4 = threadIdx.x & 3;
    int grow = mb*64 + rl; int tt = grow >> 8, b = grow & 255;
    const float* st = state + ((long)b*64 + tt)*12;
    float sv[12];
    #pragma unroll
    for (int s=0;s<12;s++) sv[s] = st[s];
    for (int d=q4*16; d<q4*16+16; ++d){
      int h = n*64 + d;
      float sum = beta_sk[h];
      #pragma unroll
      for (int s=0;s<12;s++) sum += sv[s]*W_sk[h*12+s];
      k1s[rl*65 + d] = sum;
    }
  }
  __syncthreads();
  if (threadIdx.x < 64){
    int rl = threadIdx.x; int grow = mb*64 + rl;
    const u16* qrow = q2 + (long)grow*768 + n*64;
    float d1 = 0.f, d2 = 0.f;
    for (int d=0; d<64; ++d){ float qv = bf2f(qrow[d]); d1 += qv*k1s[rl*65+d]; d2 += qv*k2s[rl*65+d]; }
    s12[(long)grow*24 + n*2 + 0] = d1*0.125f;
    s12[(long)grow*24 + n*2 + 1] = d2*0.125f;
  }
}

// ---------------- per-step stage A: kv0 | gh0 | gh1 | pr | po_b ----------------
__global__ __launch_bounds__(256) void rbn_stageA(
    const u16* __restrict__ bp, const u16* __restrict__ h0, const u16* __restrict__ h1,
    const u16* __restrict__ Wbkv, const float* __restrict__ beta_bkv,
    const u16* __restrict__ whh0, const float* __restrict__ b_hh0,
    const u16* __restrict__ whh1, const float* __restrict__ b_hh1,
    const u16* __restrict__ wpr, const float* __restrict__ b_pr,
    const u16* __restrict__ wpo,
    u16* __restrict__ kv0, float* __restrict__ gh0, float* __restrict__ gh1,
    float* __restrict__ pr, float* __restrict__ po_b)
{
  int bid = blockIdx.x;
  const u16* A; const u16* W; long ldw = 768; const float* bias; int obf; void* C; long ldc; int mb, nb;
  if (bid < 96)      { A=bp; W=Wbkv; bias=beta_bkv; obf=1; C=kv0;  ldc=1536; mb=bid/24;       nb=bid%24; }
  else if (bid<240)  { int lb=bid-96;  A=h0; W=whh0; bias=b_hh0; obf=0; C=gh0; ldc=2304; mb=lb/36; nb=lb%36; }
  else if (bid<384)  { int lb=bid-240; A=h1; W=whh1; bias=b_hh1; obf=0; C=gh1; ldc=2304; mb=lb/36; nb=lb%36; }
  else if (bid<388)  { int lb=bid-384; A=bp; W=wpr;  bias=b_pr;  obf=0; C=pr;  ldc=64;   mb=lb;    nb=0; }
  else               { int lb=bid-388; A=bp; W=wpo; ldw=1536; bias=nullptr; obf=0; C=po_b; ldc=64; mb=lb; nb=0; }
  int lane = threadIdx.x & 63, wv = threadIdx.x >> 6;
  int r16 = lane & 15, kg = lane >> 4;
  f32x4 acc[4]; for (int i=0;i<4;i++) acc[i] = (f32x4){0.f,0.f,0.f,0.f};
  int n0 = nb*64 + wv*16;
  mm64(A + (long)mb*64*768, 768, W + (long)n0*ldw, ldw, 768, acc);
  int col = n0 + r16;
  float bv = bias ? bias[col] : 0.f;
  #pragma unroll
  for (int i=0;i<4;i++)
    #pragma unroll
    for (int r=0;r<4;r++){
      long row = (long)mb*64 + i*16 + kg*4 + r;
      float v = acc[i][r] + bv;
      if (obf) ((u16*)C)[row*ldc+col] = f2bf(v);
      else     ((float*)C)[row*ldc+col] = v;
    }
}

// ---------------- per-step attention mix -> ctx ----------------
__global__ __launch_bounds__(64) void rbn_attn(const u16* __restrict__ q2, const u16* __restrict__ kv0,
    const u16* __restrict__ v1, const u16* __restrict__ v2, const float* __restrict__ s12,
    u16* __restrict__ ctx, int t)
{
  int b = blockIdx.x, d = threadIdx.x;
  long tb = (long)t*256 + b;
  for (int n=0; n<12; ++n){
    int hc = n*64 + d;
    float qv = bf2f(q2[tb*768 + hc]);
    float kv = bf2f(kv0[(long)b*1536 + hc]);
    float s0 = qv*kv;
    for (int off=32; off; off>>=1) s0 += __shfl_xor(s0, off);
    s0 *= 0.125f;
    float s1 = s12[tb*24 + n*2], s2 = s12[tb*24 + n*2 + 1];
    float m = fmaxf(s0, fmaxf(s1, s2));
    float e0 = __expf(s0-m), e1 = __expf(s1-m), e2 = __expf(s2-m);
    float inv = 1.f/(e0+e1+e2);
    float v0  = bf2f(kv0[(long)b*1536 + 768 + hc]);
    float vv1 = bf2f(v1[tb*768+hc]), vv2 = bf2f(v2[tb*768+hc]);
    ctx[(long)b*768 + hc] = f2bf((e0*v0 + e1*vv1 + e2*vv2)*inv);
  }
}

// ---------------- per-step stage C: f = ctx@w_o^T + b_o ; po_f/z/KL ----------------
__global__ __launch_bounds__(256) void rbn_stageC(
    const u16* __restrict__ ctx, const u16* __restrict__ wo, const float* __restrict__ b_o,
    const u16* __restrict__ Wc_c, const float* __restrict__ beta_c,
    const float* __restrict__ po_b, const float* __restrict__ pr, const float* __restrict__ eps,
    u16* __restrict__ f_seq, u16* __restrict__ z_seq, float* __restrict__ kl_buf, int t)
{
  __shared__ float po_s[64*65];
  int bid = blockIdx.x;
  int lane = threadIdx.x & 63, wv = threadIdx.x >> 6;
  int r16 = lane & 15, kg = lane >> 4;
  f32x4 acc[4]; for (int i=0;i<4;i++) acc[i] = (f32x4){0.f,0.f,0.f,0.f};
  if (bid < 48){
    int mb = bid/12, nb = bid%12;
    int n0 = nb*64 + wv*16;
    mm64(ctx + (long)mb*64*768, 768, wo + (long)n0*768, 768, 768, acc);
    int col = n0 + r16; float bv = b_o[col];
    #pragma unroll
    for (int i=0;i<4;i++)
      #pragma unroll
      for (int r=0;r<4;r++){
        long row = (long)mb*64 + i*16 + kg*4 + r;   // batch b
        f_seq[(row*63 + t)*768 + col] = f2bf(acc[i][r] + bv);
      }
  } else {
    int mb = bid - 48, m0 = mb*64;
    int n0 = wv*16;
    mm64(ctx + (long)m0*768, 768, Wc_c + (long)n0*768, 768, 768, acc);
    #pragma unroll
    for (int i=0;i<4;i++)
      #pragma unroll
      for (int r=0;r<4;r++)
        po_s[(i*16+kg*4+r)*65 + n0 + r16] = acc[i][r];
    __syncthreads();
    if (threadIdx.x < 64){
      int rl = threadIdx.x; int b = m0 + rl;
      float kl = 0.f;
      for (int l=0;l<32;l++){
        float mu_q = po_s[rl*65 + l]      + po_b[b*64 + l]      + beta_c[l];
        float ls_q = po_s[rl*65 + 32 + l] + po_b[b*64 + 32 + l] + beta_c[32 + l];
        float mu_p = pr[b*64 + l], ls_p = pr[b*64 + 32 + l];
        float e = eps[((long)b*63 + t)*32 + l];
        float sq = __expf(ls_q);
        float z = mu_q + sq*e;
        z_seq[((long)b*63 + t)*32 + l] = f2bf(z);
        float sp = __expf(ls_p);
        float dm = mu_q - mu_p;
        kl += ls_p - ls_q + (sq*sq + dm*dm)/(2.f*sp*sp) - 0.5f;
      }
      kl_buf[t*256 + b] = kl;
    }
  }
}

// ---------------- per-step GRU stage (0: h0 from [f,z]; 1: h1 from h0, + belief out) ----------------
template<int STAGE>
__global__ __launch_bounds__(256) void rbn_gru(const u16* __restrict__ A1, const u16* __restrict__ zs,
    const u16* __restrict__ wih, const float* __restrict__ b_ih, const float* __restrict__ gh,
    u16* __restrict__ hst, u16* __restrict__ bps, u16* __restrict__ bsq, float* __restrict__ obel, int t)
{
  int mb = blockIdx.x/12, jb = blockIdx.x%12;
  int m0 = mb*64, j0 = jb*64;
  int lane = threadIdx.x & 63, wv = threadIdx.x >> 6;
  int r16 = lane & 15, kg = lane >> 4;
  const long ldw = STAGE ? 768 : 800;
  f32x4 ar[4], az[4], an[4];
  for (int i=0;i<4;i++){ ar[i]=(f32x4){0,0,0,0}; az[i]=(f32x4){0,0,0,0}; an[i]=(f32x4){0,0,0,0}; }
  const u16* wr = wih + (long)(j0 + wv*16 + r16)*ldw + kg*8;
  const u16* wz = wr + (long)768*ldw;
  const u16* wn = wr + (long)1536*ldw;
  long lda1 = STAGE ? 768 : (long)63*768;
  const u16* ap = A1 + (STAGE ? 0 : (long)t*768) + (long)m0*lda1 + (long)r16*lda1 + kg*8;
  for (int k=0; k<768; k+=32){
    short8 br = *reinterpret_cast<const short8*>(wr + k);
    short8 bz = *reinterpret_cast<const short8*>(wz + k);
    short8 bn = *reinterpret_cast<const short8*>(wn + k);
    #pragma unroll
    for (int i=0;i<4;i++){
      short8 a = *reinterpret_cast<const short8*>(ap + (long)i*16*lda1 + k);
      ar[i]=mfma16(a,br,ar[i]); az[i]=mfma16(a,bz,az[i]); an[i]=mfma16(a,bn,an[i]);
    }
  }
  if (!STAGE){ // z part, K=32
    const u16* ap2 = zs + (long)m0*2016 + (long)t*32 + (long)r16*2016 + kg*8;
    short8 br = *reinterpret_cast<const short8*>(wr + 768);
    short8 bz = *reinterpret_cast<const short8*>(wz + 768);
    short8 bn = *reinterpret_cast<const short8*>(wn + 768);
    #pragma unroll
    for (int i=0;i<4;i++){
      short8 a = *reinterpret_cast<const short8*>(ap2 + (long)i*16*2016);
      ar[i]=mfma16(a,br,ar[i]); az[i]=mfma16(a,bz,az[i]); an[i]=mfma16(a,bn,an[i]);
    }
  }
  int col = j0 + wv*16 + r16;
  float bir = b_ih[col], biz = b_ih[768+col], bin_ = b_ih[1536+col];
  #pragma unroll
  for (int i=0;i<4;i++)
    #pragma unroll
    for (int r=0;r<4;r++){
      int grow = m0 + i*16 + kg*4 + r;
      const float* ghrow = gh + (long)grow*2304;
      float rr = sigm(ar[i][r] + bir + ghrow[col]);
      float zz = sigm(az[i][r] + biz + ghrow[768+col]);
      float nn = tanhf(an[i][r] + bin_ + rr*ghrow[1536+col]);
      float hp = bf2f(hst[(long)grow*768 + col]);
      float hn = (1.f-zz)*nn + zz*hp;
      hst[(long)grow*768 + col] = f2bf(hn);
      if (STAGE){
        float bt = fmaxf(hn, 0.f);
        bps[(long)grow*768 + col] = f2bf(bt);
        long o = ((long)grow*63 + t)*768 + col;
        bsq[o] = f2bf(bt);
        obel[o] = bt;
      }
    }
}

// ---------------- decoder ----------------
__global__ __launch_bounds__(256) void rbn_dec1(const u16* __restrict__ b_seq, const u16* __restrict__ z_seq,
    const u16* __restrict__ wd1, const float* __restrict__ b_d1, u16* __restrict__ hdec)
{
  int mb = blockIdx.x/12, nb = blockIdx.x%12;
  int lane = threadIdx.x & 63, wv = threadIdx.x >> 6;
  int r16 = lane & 15, kg = lane >> 4;
  f32x4 acc[4]; for (int i=0;i<4;i++) acc[i] = (f32x4){0.f,0.f,0.f,0.f};
  int n0 = nb*64 + wv*16;
  mm64(b_seq + (long)mb*64*768, 768, wd1 + (long)n0*800, 800, 768, acc);
  mm64(z_seq + (long)mb*64*32,  32,  wd1 + (long)n0*800 + 768, 800, 32, acc);
  int col = n0 + r16; float bv = b_d1[col];
  #pragma unroll
  for (int i=0;i<4;i++)
    #pragma unroll
    for (int r=0;r<4;r++){
      long row = (long)mb*64 + i*16 + kg*4 + r;
      float x = acc[i][r] + bv;
      float g = 0.5f*x*(1.f + erff(x*0.70710678118f));
      hdec[row*768 + col] = f2bf(g);
    }
}
__global__ __launch_bounds__(256) void rbn_pred(const u16* __restrict__ hdec, const u16* __restrict__ wd2,
    const float* __restrict__ b_d2, const float* __restrict__ visual,
    float* __restrict__ out_pred, float* __restrict__ racc)
{
  int mb = blockIdx.x/12, nb = blockIdx.x%12;
  int lane = threadIdx.x & 63, wv = threadIdx.x >> 6;
  int r16 = lane & 15, kg = lane >> 4;
  f32x4 acc[4]; for (int i=0;i<4;i++) acc[i] = (f32x4){0.f,0.f,0.f,0.f};
  int n0 = nb*64 + wv*16;
  mm64(hdec + (long)mb*64*768, 768, wd2 + (long)n0*768, 768, 768, acc);
  int col = n0 + r16; float bv = b_d2[col];
  float loc = 0.f;
  #pragma unroll
  for (int i=0;i<4;i++)
    #pragma unroll
    for (int r=0;r<4;r++){
      long row = (long)mb*64 + i*16 + kg*4 + r;
      int b = (int)(row/63), tt = (int)(row%63);
      float v = acc[i][r] + bv;
      out_pred[row*768 + col] = v;
      float d = v - visual[((long)b*64 + tt + 1)*768 + col];
      loc += d*d;
    }
  __shared__ float red[256];
  red[threadIdx.x] = loc; __syncthreads();
  for (int w=128; w; w>>=1){ if (threadIdx.x<w) red[threadIdx.x]+=red[threadIdx.x+w]; __syncthreads(); }
  if (threadIdx.x==0) atomicAdd(racc, red[0]);
}

// ---------------- NCE: per-b Gram with online LSE ----------------
__global__ __launch_bounds__(256) void rbn_nce(const u16* __restrict__ f_seq, float* __restrict__ nce_p){
  int b = blockIdx.x;
  const u16* F = f_seq + (long)b*63*768;
  __shared__ float inorm[64];
  __shared__ u16 sb[16*776];
  __shared__ u16 tbl[16*776];
  __shared__ float red[256];
  int tid = threadIdx.x;
  { // norms: 4 threads per row
    int srow = tid >> 2, q4 = tid & 3;
    float p = 0.f;
    if (srow < 63){ const u16* fr = F + (long)srow*768 + q4*192; for (int d=0; d<192; ++d){ float v=bf2f(fr[d]); p += v*v; } }
    red[tid] = p; __syncthreads();
    if (tid < 63){
      float n2 = red[tid*4]+red[tid*4+1]+red[tid*4+2]+red[tid*4+3];
      inorm[tid] = 1.f/fmaxf(sqrtf(n2), 1e-12f);
    }
    __syncthreads();
  }
  float acc = 0.f;
  int ti_ = tid >> 4, tj = tid & 15;
  for (int sbk=0; sbk<4; ++sbk){
    int sbase = sbk*16;
    __syncthreads();
    for (int idx=tid; idx<16*768; idx+=256){
      int rr = idx/768, dd = idx%768; int sg = sbase + rr;
      sb[rr*776+dd] = (sg<63) ? f2bf(bf2f(F[(long)sg*768 + dd]) * inorm[sg]) : (u16)0;
    }
    float m_run = -1e30f, s_run = 0.f, tv = 0.f;
    for (int tbk=0; tbk<4; ++tbk){
      int tbase = tbk*16;
      __syncthreads();
      for (int idx=tid; idx<16*768; idx+=256){
        int rr = idx/768, dd = idx%768; int tg = tbase + rr;
        tbl[rr*776+dd] = (tg<63) ? f2bf(bf2f(F[(long)tg*768 + dd]) * inorm[tg]) : (u16)0;
      }
      __syncthreads();
      float dot = 0.f;
      const u16* sr = sb + ti_*776; const u16* tr = tbl + tj*776;
      for (int d=0; d<768; ++d) dot += bf2f(sr[d])*bf2f(tr[d]);
      dot *= 10.f; // /TEMP
      int tg = tbase + tj;
      float dval = (tg < 63) ? dot : -1e30f;
      float bm = dval;
      for (int off=1; off<16; off<<=1) bm = fmaxf(bm, __shfl_xor(bm, off));
      float mn = fmaxf(m_run, bm);
      float ex = (tg < 63) ? __expf(dval - mn) : 0.f;
      for (int off=1; off<16; off<<=1) ex += __shfl_xor(ex, off);
      s_run = s_run*__expf(m_run - mn) + ex;
      m_run = mn;
      int sg = sbase + ti_;
      float tc = (tg == sg+1) ? dot : 0.f;
      for (int off=1; off<16; off<<=1) tc += __shfl_xor(tc, off);
      tv += tc;
    }
    int sg = sbase + ti_;
    if (tj == 0 && sg < 62) acc += tv - (m_run + logf(s_run));
  }
  __syncthreads();
  red[tid] = acc; __syncthreads();
  for (int w=128; w; w>>=1){ if (tid<w) red[tid]+=red[tid+w]; __syncthreads(); }
  if (tid==0) nce_p[b] = red[0];
}

__global__ __launch_bounds__(256) void rbn_final(const float* __restrict__ kl_buf,
    const float* __restrict__ nce_p, const float* __restrict__ racc, float* __restrict__ out)
{
  __shared__ float red[256]; __shared__ float klv;
  int tid = threadIdx.x;
  float s = 0.f;
  for (int i=tid; i<16128; i+=256) s += kl_buf[i];
  red[tid] = s; __syncthreads();
  for (int w=128; w; w>>=1){ if (tid<w) red[tid]+=red[tid+w]; __syncthreads(); }
  if (tid==0) klv = red[0]/(63.f*256.f);
  __syncthreads();
  red[tid] = nce_p[tid]; __syncthreads();
  for (int w=128; w; w>>=1){ if (tid<w) red[tid]+=red[tid+w]; __syncthreads(); }
  if (tid==0){
    float nce = -red[0]/(256.f*62.f);
    float recon = racc[0]/(256.f*63.f*768.f);
    out[0] = recon + klv + nce; out[1] = recon; out[2] = klv; out[3] = nce;
  }
}

// =====================================================================
extern "C" void kernel_launch(void* const* d_in, const int* in_sizes, int n_in,
                              void* d_out, int out_size, void* d_ws, size_t ws_size,
                              hipStream_t stream)
{
  const float* visual = (const float*)d_in[0];
  const float* state  = (const float*)d_in[1];
  const float* eps    = (const float*)d_in[2];
  const float* w_vis = (const float*)d_in[3];  const float* b_vis = (const float*)d_in[4];
  const float* w_st  = (const float*)d_in[5];  const float* b_st  = (const float*)d_in[6];
  const float* w_bt  = (const float*)d_in[7];  const float* b_bt  = (const float*)d_in[8];
  const float* w_q   = (const float*)d_in[9];  const float* b_q   = (const float*)d_in[10];
  const float* w_k   = (const float*)d_in[11]; const float* b_k   = (const float*)d_in[12];
  const float* w_v   = (const float*)d_in[13]; const float* b_v   = (const float*)d_in[14];
  const float* w_o   = (const float*)d_in[15]; const float* b_o   = (const float*)d_in[16];
  const float* w_pr  = (const float*)d_in[17]; const float* b_pr  = (const float*)d_in[18];
  const float* w_po  = (const float*)d_in[19]; const float* b_po  = (const float*)d_in[20];
  const float* w_ih0 = (const float*)d_in[21]; const float* w_hh0 = (const float*)d_in[22];
  const float* b_ih0 = (const float*)d_in[23]; const float* b_hh0 = (const float*)d_in[24];
  const float* w_ih1 = (const float*)d_in[25]; const float* w_hh1 = (const float*)d_in[26];
  const float* b_ih1 = (const float*)d_in[27]; const float* b_hh1 = (const float*)d_in[28];
  const float* w_d1  = (const float*)d_in[29]; const float* b_d1  = (const float*)d_in[30];
  const float* w_d2  = (const float*)d_in[31]; const float* b_d2  = (const float*)d_in[32];

  float* out = (float*)d_out;
  float* out_pred   = out + 4;
  float* out_belief = out + 4 + 12386304;

  // ---- carve workspace ----
  char* p = (char*)d_ws;
  auto alloc = [&](size_t bytes)->char*{ char* r = p; p += (bytes + 255) & ~(size_t)255; return r; };
  auto aU = [&](size_t elems)->u16*  { return (u16*)alloc(elems*2); };
  auto aF = [&](size_t elems)->float*{ return (float*)alloc(elems*4); };

  u16* wb_q   = aU(589824);  u16* wb_k   = aU(589824);  u16* wb_v   = aU(589824);
  u16* wb_o   = aU(589824);  u16* wb_po  = aU(98304);   u16* wb_pr  = aU(49152);
  u16* wb_hh0 = aU(1769472); u16* wb_ih0 = aU(1843200);
  u16* wb_hh1 = aU(1769472); u16* wb_ih1 = aU(1769472);
  u16* wb_d1  = aU(614400);  u16* wb_d2  = aU(589824);
  u16* wb_vis_t = aU(589824); u16* wb_bt_t = aU(589824); u16* wb_o_t = aU(589824);
  u16* Wc_vq  = aU(589824);  u16* Wc_vk  = aU(589824);  u16* Wc_vv  = aU(589824);
  u16* Wc_bkv = aU(1179648); u16* Wc_c   = aU(49152);
  u16* vis_tb = aU(12386304);            // reused as hdec in post phase
  u16* q2     = aU(12386304);
  u16* v1     = aU(12386304);
  u16* v2     = aU(12386304);
  u16* f_seq  = aU(12386304);
  u16* b_seq  = aU(12386304);
  u16* z_seq  = aU(516096);
  u16* kv0    = aU(393216);
  u16* ctx    = aU(196608);
  u16* bp     = aU(196608);
  u16* h0     = aU(196608);
  u16* h1     = aU(196608);
  u16* hdec   = vis_tb;

  float* W_sk = aF(9216);  float* W_sv = aF(9216);
  float* beta_vq = aF(768); float* beta_vk = aF(768); float* beta_vv = aF(768);
  float* beta_bkv = aF(1536);
  float* beta_sk = aF(768); float* beta_sv = aF(768);
  float* beta_c  = aF(64);
  float* s12   = aF(387072);
  float* gh0   = aF(589824); float* gh1 = aF(589824);
  float* pr    = aF(16384);  float* po_b = aF(16384);
  float* kl_buf = aF(16128);
  float* nce_p  = aF(256);
  float* recon_acc = aF(8);
  (void)ws_size; (void)out_size; (void)n_in; (void)in_sizes;

  // ---- pre-pass ----
  rbn_zero<<<768,256,0,stream>>>(bp, h0, h1, recon_acc);

  auto CVT = [&](const float* in, u16* o, int n){ rbn_cvt<<<(n+255)/256,256,0,stream>>>(in,o,n); };
  CVT(w_q, wb_q, 589824);   CVT(w_k, wb_k, 589824);   CVT(w_v, wb_v, 589824);
  CVT(w_o, wb_o, 589824);   CVT(w_po, wb_po, 98304);  CVT(w_pr, wb_pr, 49152);
  CVT(w_hh0, wb_hh0, 1769472); CVT(w_ih0, wb_ih0, 1843200);
  CVT(w_hh1, wb_hh1, 1769472); CVT(w_ih1, wb_ih1, 1769472);
  CVT(w_d1, wb_d1, 614400); CVT(w_d2, wb_d2, 589824);
  rbn_cvtT<<<(589824+255)/256,256,0,stream>>>(w_vis, wb_vis_t, 768, 768);
  rbn_cvtT<<<(589824+255)/256,256,0,stream>>>(w_bt,  wb_bt_t,  768, 768);
  rbn_cvtT<<<(589824+255)/256,256,0,stream>>>(w_o,   wb_o_t,   768, 768);

  rbn_wsmall<<<768,64,0,stream>>>(w_k, w_st, W_sk);
  rbn_wsmall<<<768,64,0,stream>>>(w_v, w_st, W_sv);

  rbn_matvec<<<768,256,0,stream>>>(w_q, 768, 768, b_vis, b_q, beta_vq);
  rbn_matvec<<<768,256,0,stream>>>(w_k, 768, 768, b_vis, b_k, beta_vk);
  rbn_matvec<<<768,256,0,stream>>>(w_v, 768, 768, b_vis, b_v, beta_vv);
  rbn_matvec<<<768,256,0,stream>>>(w_k, 768, 768, b_bt, b_k, beta_bkv);
  rbn_matvec<<<768,256,0,stream>>>(w_v, 768, 768, b_bt, b_v, beta_bkv + 768);
  rbn_matvec<<<768,256,0,stream>>>(w_k, 768, 768, b_st, b_k, beta_sk);
  rbn_matvec<<<768,256,0,stream>>>(w_v, 768, 768, b_st, b_v, beta_sv);
  rbn_matvec<<<64,256,0,stream>>>(w_po + 768, 1536, 768, b_o, b_po, beta_c);

  // combined weights (bf16 GEMMs)
  rbn_gemm<1><<<144,256,0,stream>>>(wb_q, 768, wb_vis_t, 768, 768, nullptr, Wc_vq, 768, 12);
  rbn_gemm<1><<<144,256,0,stream>>>(wb_k, 768, wb_vis_t, 768, 768, nullptr, Wc_vk, 768, 12);
  rbn_gemm<1><<<144,256,0,stream>>>(wb_v, 768, wb_vis_t, 768, 768, nullptr, Wc_vv, 768, 12);
  rbn_gemm<1><<<144,256,0,stream>>>(wb_k, 768, wb_bt_t, 768, 768, nullptr, Wc_bkv, 768, 12);
  rbn_gemm<1><<<144,256,0,stream>>>(wb_v, 768, wb_bt_t, 768, 768, nullptr, Wc_bkv + (long)768*768, 768, 12);
  rbn_gemm<1><<<12,256,0,stream>>>(wb_po + 768, 1536, wb_o_t, 768, 768, nullptr, Wc_c, 768, 12);

  // projections for all steps
  rbn_cvt_vis<<<16128,256,0,stream>>>(visual, vis_tb);
  rbn_gemm<1><<<3024,256,0,stream>>>(vis_tb, 768, Wc_vq, 768, 768, beta_vq, q2, 768, 12);
  rbn_gemm<1><<<3024,256,0,stream>>>(vis_tb, 768, Wc_vv, 768, 768, beta_vv, v2, 768, 12);
  rbn_v1<<<48384,256,0,stream>>>(state, W_sv, beta_sv, v1);
  rbn_s12<<<3024,256,0,stream>>>(vis_tb, Wc_vk, beta_vk, W_sk, beta_sk, state, q2, s12);

  // ---- sequential scan ----
  for (int t=0; t<63; ++t){
    rbn_stageA<<<392,256,0,stream>>>(bp, h0, h1, Wc_bkv, beta_bkv, wb_hh0, b_hh0,
                                     wb_hh1, b_hh1, wb_pr, b_pr, wb_po,
                                     kv0, gh0, gh1, pr, po_b);
    rbn_attn<<<256,64,0,stream>>>(q2, kv0, v1, v2, s12, ctx, t);
    rbn_stageC<<<52,256,0,stream>>>(ctx, wb_o, b_o, Wc_c, beta_c, po_b, pr, eps,
                                    f_seq, z_seq, kl_buf, t);
    rbn_gru<0><<<48,256,0,stream>>>(f_seq, z_seq, wb_ih0, b_ih0, gh0, h0,
                                    nullptr, nullptr, nullptr, t);
    rbn_gru<1><<<48,256,0,stream>>>(h0, nullptr, wb_ih1, b_ih1, gh1, h1,
                                    bp, b_seq, out_belief, t);
  }

  // ---- post ----
  rbn_dec1<<<3024,256,0,stream>>>(b_seq, z_seq, wb_d1, b_d1, hdec);
  rbn_pred<<<3024,256,0,stream>>>(hdec, wb_d2, b_d2, visual, out_pred, recon_acc);
  rbn_nce<<<256,256,0,stream>>>(f_seq, nce_p);
  rbn_final<<<1,256,0,stream>>>(kl_buf, nce_p, recon_acc, out);
}

// Round 2
// 6874.214 us; speedup vs baseline: 1.4007x; 1.4007x over previous
//
#include <hip/hip_runtime.h>

typedef unsigned short u16;
typedef __attribute__((ext_vector_type(8))) short short8;
typedef __attribute__((ext_vector_type(4))) float f32x4;

#define DEVI __device__ __forceinline__

DEVI u16 f2bf(float f){ union{float f;unsigned u;} v; v.f=f; unsigned r=v.u+0x7FFFu+((v.u>>16)&1u); return (u16)(r>>16); }
DEVI float bf2f(u16 h){ union{unsigned u;float f;} v; v.u=((unsigned)h)<<16; return v.f; }
DEVI float sigm(float x){ return 1.f/(1.f+__expf(-x)); }
DEVI f32x4 mfma16(short8 a, short8 b, f32x4 c){ return __builtin_amdgcn_mfma_f32_16x16x32_bf16(a,b,c,0,0,0); }

// stage 64x64 bf16 tile global->LDS (row stride 72 elems = 144B: 2-way bank alias, free)
DEVI void stage64(u16* lds, const u16* __restrict__ A, long lda){
  int t = threadIdx.x;
  #pragma unroll
  for (int i=0;i<2;i++){
    int idx = t + i*256;
    int row = idx >> 3, c8 = (idx & 7)*8;
    *(short8*)(lds + row*72 + c8) = *(const short8*)(A + (long)row*lda + c8);
  }
}

// LDS-staged 64(M)x64(N) GEMM: acc += A[64xK] * W[16 rows owned by wave]^T
// caller pre-offsets A to tile row 0, Wn to row (n0+wv*16); all 256 threads participate.
DEVI void mm64s(u16* lds, const u16* __restrict__ A, long lda,
                const u16* __restrict__ Wn, long ldw, int K, f32x4 acc[4])
{
  int lane = threadIdx.x & 63;
  int r16 = lane & 15, kg = lane >> 4;
  const u16* wp = Wn + (long)r16*ldw + kg*8;
  for (int k=0; k<K; k+=64){
    stage64(lds, A + k, lda);
    __syncthreads();
    #pragma unroll
    for (int kk=0; kk<64; kk+=32){
      short8 b = *(const short8*)(wp + k + kk);
      #pragma unroll
      for (int i=0;i<4;i++){
        short8 a = *(const short8*)(lds + (i*16 + r16)*72 + kg*8 + kk);
        acc[i] = mfma16(a, b, acc[i]);
      }
    }
    __syncthreads();
  }
}

// ---------------- generic GEMM: C = A @ W^T + bias ----------------
// MODE 0: f32 out; 1: bf16 out; 2: bf16 out with tb->bt row remap (rows = 63*256)
template<int MODE>
__global__ __launch_bounds__(256) void rbn_gemm(const u16* __restrict__ A, long lda,
    const u16* __restrict__ W, long ldw, int K, const float* __restrict__ bias,
    void* __restrict__ C, long ldc, int nbN)
{
  __shared__ u16 aS[64*72];
  int mb = blockIdx.x / nbN, nb = blockIdx.x % nbN;
  int lane = threadIdx.x & 63, wv = threadIdx.x >> 6;
  int r16 = lane & 15, kg = lane >> 4;
  f32x4 acc[4]; for (int i=0;i<4;i++) acc[i] = (f32x4){0.f,0.f,0.f,0.f};
  int n0 = nb*64 + wv*16;
  mm64s(aS, A + (long)mb*64*lda, lda, W + (long)n0*ldw, ldw, K, acc);
  int col = n0 + r16;
  float bv = bias ? bias[col] : 0.f;
  #pragma unroll
  for (int i=0;i<4;i++)
    #pragma unroll
    for (int r=0;r<4;r++){
      long row = (long)mb*64 + i*16 + kg*4 + r;
      float v = acc[i][r] + bv;
      if (MODE == 0) ((float*)C)[row*ldc+col] = v;
      else if (MODE == 1) ((u16*)C)[row*ldc+col] = f2bf(v);
      else {
        long t = row >> 8, b = row & 255;
        ((u16*)C)[(b*63 + t)*ldc + col] = f2bf(v);
      }
    }
}

// ---------------- misc small kernels ----------------
__global__ void rbn_cvt8(const float* __restrict__ in, u16* __restrict__ out, int n8){
  int i = blockIdx.x*256 + threadIdx.x; if (i >= n8) return;
  const float* s = in + (long)i*8;
  short8 o;
  #pragma unroll
  for (int u=0;u<8;u++) o[u] = (short)f2bf(s[u]);
  *(short8*)(out + (long)i*8) = o;
}
// in [R][C] fp32 -> out [C][R] bf16
__global__ void rbn_cvtT(const float* __restrict__ in, u16* __restrict__ out, int R, int C){
  int i = blockIdx.x*256 + threadIdx.x;
  if (i < R*C){ int c = i / R, r = i % R; out[i] = f2bf(in[(long)r*C + c]); }
}
// w_ih0[2304][800] cols 0..768 -> bf16 [2304][768]
__global__ void rbn_cvt_ih0f(const float* __restrict__ in, u16* __restrict__ out){
  int i = blockIdx.x*256 + threadIdx.x;
  if (i >= 2304*96) return;
  int j = i/96, c8 = (i%96)*8;
  const float* s = in + (long)j*800 + c8;
  short8 o;
  #pragma unroll
  for (int u=0;u<8;u++) o[u] = (short)f2bf(s[u]);
  *(short8*)(out + (long)j*768 + c8) = o;
}
// w_ih0[2304][800] cols 768..800 -> bf16 [2304][32]
__global__ void rbn_cvt_wz(const float* __restrict__ in, u16* __restrict__ out){
  int i = blockIdx.x*256 + threadIdx.x;
  if (i >= 2304*4) return;
  int j = i/4, c8 = (i%4)*8;
  const float* s = in + (long)j*800 + 768 + c8;
  short8 o;
  #pragma unroll
  for (int u=0;u<8;u++) o[u] = (short)f2bf(s[u]);
  *(short8*)(out + (long)j*32 + c8) = o;
}
// out[i] = sum_k W[i*ldk+k]*u[k] + add[i]
__global__ __launch_bounds__(256) void rbn_matvec(const float* __restrict__ W, long ldk, int K,
    const float* __restrict__ u, const float* __restrict__ add, float* __restrict__ out)
{
  int i = blockIdx.x;
  float p = 0.f;
  for (int k=threadIdx.x; k<K; k+=256) p += W[(long)i*ldk + k]*u[k];
  __shared__ float red[256];
  red[threadIdx.x] = p; __syncthreads();
  for (int w=128; w; w>>=1){ if (threadIdx.x<w) red[threadIdx.x]+=red[threadIdx.x+w]; __syncthreads(); }
  if (threadIdx.x==0) out[i] = red[0] + (add ? add[i] : 0.f);
}
// out[768][12] = wk(768x768) @ wst(768x12)
__global__ void rbn_wsmall(const float* __restrict__ wk, const float* __restrict__ wst, float* __restrict__ out){
  int i = blockIdx.x, j = threadIdx.x;
  if (j < 12){
    float s = 0.f;
    for (int k=0;k<768;k++) s += wk[(long)i*768+k]*wst[(long)k*12+j];
    out[i*12+j] = s;
  }
}
__global__ void rbn_zero(u16* bp, u16* h0, u16* h1, float* racc){
  int i = blockIdx.x*256 + threadIdx.x;
  if (i < 196608){ bp[i]=0; h0[i]=0; h1[i]=0; }
  if (i == 0) racc[0] = 0.f;
}
// visual (B,T,V) fp32 -> vis_tb [S][B][768] bf16  (row = t*256+b)
__global__ __launch_bounds__(256) void rbn_cvt_vis(const float* __restrict__ vis, u16* __restrict__ vt){
  int row = blockIdx.x; int t = row >> 8, b = row & 255;
  const float* src = vis + ((long)b*64 + t)*768;
  u16* dst = vt + (long)row*768;
  for (int v=threadIdx.x; v<768; v+=256) dst[v] = f2bf(src[v]);
}
// v1[t,b,h] = sum_s state[b,t,s]*Wsv[h,s] + beta[h]
__global__ __launch_bounds__(256) void rbn_v1(const float* __restrict__ state, const float* __restrict__ Wsv,
    const float* __restrict__ beta, u16* __restrict__ v1)
{
  long g = (long)blockIdx.x*256 + threadIdx.x;
  if (g >= (long)16128*768) return;
  int row = (int)(g/768), h = (int)(g%768);
  int t = row >> 8, b = row & 255;
  const float* st = state + ((long)b*64 + t)*12;
  float s = beta[h];
  #pragma unroll
  for (int k=0;k<12;k++) s += st[k]*Wsv[h*12+k];
  v1[g] = f2bf(s);
}
// k2-tile via staged GEMM + k1-tile via K=12, then s12 = SCALE * q2 . k{1,2}
__global__ __launch_bounds__(256) void rbn_s12(const u16* __restrict__ vis_tb, const u16* __restrict__ Wc_vk,
    const float* __restrict__ beta_vk, const float* __restrict__ W_sk, const float* __restrict__ beta_sk,
    const float* __restrict__ state, const u16* __restrict__ q2, float* __restrict__ s12)
{
  int mb = blockIdx.x/12, n = blockIdx.x%12;
  __shared__ u16 stg[64*72];
  __shared__ float k2s[64*65];
  __shared__ float k1s[64*65];
  int lane = threadIdx.x & 63, wv = threadIdx.x >> 6;
  int r16 = lane & 15, kg = lane >> 4;
  f32x4 acc[4]; for (int i=0;i<4;i++) acc[i] = (f32x4){0.f,0.f,0.f,0.f};
  int n0 = n*64 + wv*16;
  mm64s(stg, vis_tb + (long)mb*64*768, 768, Wc_vk + (long)n0*768, 768, 768, acc);
  #pragma unroll
  for (int i=0;i<4;i++)
    #pragma unroll
    for (int r=0;r<4;r++)
      k2s[(i*16+kg*4+r)*65 + wv*16 + r16] = acc[i][r] + beta_vk[n0 + r16];
  // k1
  {
    int rl = threadIdx.x >> 2, q4 = threadIdx.x & 3;
    int grow = mb*64 + rl; int tt = grow >> 8, b = grow & 255;
    const float* st = state + ((long)b*64 + tt)*12;
    float sv[12];
    #pragma unroll
    for (int s=0;s<12;s++) sv[s] = st[s];
    for (int d=q4*16; d<q4*16+16; ++d){
      int h = n*64 + d;
      float sum = beta_sk[h];
      #pragma unroll
      for (int s=0;s<12;s++) sum += sv[s]*W_sk[h*12+s];
      k1s[rl*65 + d] = sum;
    }
  }
  __syncthreads();
  if (threadIdx.x < 64){
    int rl = threadIdx.x; int grow = mb*64 + rl;
    const u16* qrow = q2 + (long)grow*768 + n*64;
    float d1 = 0.f, d2 = 0.f;
    for (int d=0; d<64; ++d){ float qv = bf2f(qrow[d]); d1 += qv*k1s[rl*65+d]; d2 += qv*k2s[rl*65+d]; }
    s12[(long)grow*24 + n*2 + 0] = d1*0.125f;
    s12[(long)grow*24 + n*2 + 1] = d2*0.125f;
  }
}

// ---------------- per-step stage A: kv0 | gh0 | gh1 | pr | po_b ----------------
__global__ __launch_bounds__(256) void rbn_stepA(
    const u16* __restrict__ bp, const u16* __restrict__ h0, const u16* __restrict__ h1,
    const u16* __restrict__ Wbkv, const float* __restrict__ beta_bkv,
    const u16* __restrict__ whh0, const float* __restrict__ b_hh0,
    const u16* __restrict__ whh1, const float* __restrict__ b_hh1,
    const u16* __restrict__ wpr, const float* __restrict__ b_pr,
    const u16* __restrict__ wpo,
    u16* __restrict__ kv0, float* __restrict__ gh0, float* __restrict__ gh1,
    float* __restrict__ pr, float* __restrict__ po_b)
{
  __shared__ u16 aS[64*72];
  int bid = blockIdx.x;
  const u16* A; const u16* W; long ldw = 768; const float* bias; int obf; void* C; long ldc; int mb, nb;
  if (bid < 96)      { A=bp; W=Wbkv; bias=beta_bkv; obf=1; C=kv0;  ldc=1536; mb=bid/24;       nb=bid%24; }
  else if (bid<240)  { int lb=bid-96;  A=h0; W=whh0; bias=b_hh0; obf=0; C=gh0; ldc=2304; mb=lb/36; nb=lb%36; }
  else if (bid<384)  { int lb=bid-240; A=h1; W=whh1; bias=b_hh1; obf=0; C=gh1; ldc=2304; mb=lb/36; nb=lb%36; }
  else if (bid<388)  { int lb=bid-384; A=bp; W=wpr;  bias=b_pr;  obf=0; C=pr;  ldc=64;   mb=lb;    nb=0; }
  else               { int lb=bid-388; A=bp; W=wpo; ldw=1536; bias=nullptr; obf=0; C=po_b; ldc=64; mb=lb; nb=0; }
  int lane = threadIdx.x & 63, wv = threadIdx.x >> 6;
  int r16 = lane & 15, kg = lane >> 4;
  f32x4 acc[4]; for (int i=0;i<4;i++) acc[i] = (f32x4){0.f,0.f,0.f,0.f};
  int n0 = nb*64 + wv*16;
  mm64s(aS, A + (long)mb*64*768, 768, W + (long)n0*ldw, ldw, 768, acc);
  int col = n0 + r16;
  float bv = bias ? bias[col] : 0.f;
  #pragma unroll
  for (int i=0;i<4;i++)
    #pragma unroll
    for (int r=0;r<4;r++){
      long row = (long)mb*64 + i*16 + kg*4 + r;
      float v = acc[i][r] + bv;
      if (obf) ((u16*)C)[row*ldc+col] = f2bf(v);
      else     ((float*)C)[row*ldc+col] = v;
    }
}

// ---------------- per-step stage C: attn(ctx) + gi + posterior/z/KL + GRU0 -> h0' ----------------
__global__ __launch_bounds__(256) void rbn_stepC(
    const u16* __restrict__ q2, const u16* __restrict__ kv0,
    const u16* __restrict__ v1, const u16* __restrict__ v2,
    const float* __restrict__ s12,
    const u16* __restrict__ Wcf, const float* __restrict__ beta_g,
    const u16* __restrict__ Wcc, const float* __restrict__ beta_c,
    const u16* __restrict__ wz,
    const float* __restrict__ po_b, const float* __restrict__ pr,
    const float* __restrict__ eps, const float* __restrict__ gh0,
    u16* __restrict__ h0, u16* __restrict__ ctx_seq, u16* __restrict__ z_seq,
    float* __restrict__ kl_buf, int t)
{
  int mb = blockIdx.x / 12, jb = blockIdx.x % 12;
  int m0 = mb*32, j0 = jb*64;
  int tid = threadIdx.x;
  int lane = tid & 63, wv = tid >> 6;
  int r16 = lane & 15, kg = lane >> 4;

  __shared__ float eS[32][12][3];
  __shared__ u16 ctxS[32*72];
  __shared__ float poS[32][68];
  __shared__ u16 zS[32*40];

  // ---- softmax weights E (per row, per head) ----
  {
    int r = tid & 31, h8 = tid >> 5;
    long tb0 = (long)t*256 + m0;
    for (int n = h8; n < 12; n += 8){
      const u16* qp = q2 + (tb0 + r)*768 + n*64;
      const u16* kp = kv0 + (long)(m0 + r)*1536 + n*64;
      float s0 = 0.f;
      for (int c=0;c<64;c+=8){
        short8 qa = *(const short8*)(qp+c);
        short8 ka = *(const short8*)(kp+c);
        #pragma unroll
        for (int u=0;u<8;u++) s0 += bf2f((u16)qa[u])*bf2f((u16)ka[u]);
      }
      s0 *= 0.125f;
      float s1 = s12[(tb0+r)*24 + n*2], s2 = s12[(tb0+r)*24 + n*2+1];
      float m = fmaxf(s0, fmaxf(s1,s2));
      float e0=__expf(s0-m), e1=__expf(s1-m), e2=__expf(s2-m);
      float inv = 1.f/(e0+e1+e2);
      eS[r][n][0]=e0*inv; eS[r][n][1]=e1*inv; eS[r][n][2]=e2*inv;
    }
  }
  __syncthreads();

  f32x4 aR[2], aZ[2], aN[2], aP[2];
  #pragma unroll
  for (int i=0;i<2;i++){ aR[i]=(f32x4){0,0,0,0}; aZ[i]=(f32x4){0,0,0,0}; aN[i]=(f32x4){0,0,0,0}; aP[i]=(f32x4){0,0,0,0}; }
  const u16* wrp = Wcf + (long)(j0 + wv*16 + r16)*768 + kg*8;
  const u16* wzp = wrp + (long)768*768;
  const u16* wnp = wrp + (long)1536*768;
  const u16* wpp = Wcc + (long)(wv*16 + r16)*768 + kg*8;

  for (int n=0;n<12;n++){            // k-chunk n == head n (cols n*64..n*64+64)
    { // build ctx chunk 32x64 into LDS
      int r = tid >> 3, c8 = (tid & 7)*8;
      int b = m0 + r; long tb = (long)t*256 + b;
      float e0 = eS[r][n][0], e1 = eS[r][n][1], e2 = eS[r][n][2];
      short8 a0 = *(const short8*)(kv0 + (long)b*1536 + 768 + n*64 + c8);
      short8 a1 = *(const short8*)(v1 + tb*768 + n*64 + c8);
      short8 a2 = *(const short8*)(v2 + tb*768 + n*64 + c8);
      short8 o;
      #pragma unroll
      for (int u=0;u<8;u++)
        o[u] = (short)f2bf(e0*bf2f((u16)a0[u]) + e1*bf2f((u16)a1[u]) + e2*bf2f((u16)a2[u]));
      *(short8*)(ctxS + r*72 + c8) = o;
      if (jb == 0) *(short8*)(ctx_seq + tb*768 + n*64 + c8) = o;
    }
    __syncthreads();
    #pragma unroll
    for (int kk=0;kk<64;kk+=32){
      int k = n*64 + kk;
      short8 bR = *(const short8*)(wrp + k);
      short8 bZ = *(const short8*)(wzp + k);
      short8 bN = *(const short8*)(wnp + k);
      short8 bP = *(const short8*)(wpp + k);
      #pragma unroll
      for (int i=0;i<2;i++){
        short8 a = *(const short8*)(ctxS + (i*16 + r16)*72 + kg*8 + kk);
        aR[i]=mfma16(a,bR,aR[i]); aZ[i]=mfma16(a,bZ,aZ[i]);
        aN[i]=mfma16(a,bN,aN[i]); aP[i]=mfma16(a,bP,aP[i]);
      }
    }
    __syncthreads();
  }

  // posterior -> z (+ KL on jb==0)
  #pragma unroll
  for (int i=0;i<2;i++)
    #pragma unroll
    for (int r=0;r<4;r++)
      poS[i*16+kg*4+r][wv*16+r16] = aP[i][r];
  __syncthreads();
  if (tid < 32){
    int r = tid; int b = m0 + r;
    float kl = 0.f;
    for (int l=0;l<32;l++){
      float mu_q = poS[r][l]      + po_b[b*64+l]      + beta_c[l];
      float ls_q = poS[r][32+l]   + po_b[b*64+32+l]   + beta_c[32+l];
      float e = eps[((long)b*63+t)*32 + l];
      float sq = __expf(ls_q);
      float z = mu_q + sq*e;
      u16 zb = f2bf(z);
      zS[r*40 + l] = zb;
      if (jb == 0){
        z_seq[((long)b*63+t)*32 + l] = zb;
        float mu_p = pr[b*64+l], ls_p = pr[b*64+32+l];
        float sp = __expf(ls_p);
        float dm = mu_q - mu_p;
        kl += ls_p - ls_q + (sq*sq + dm*dm)/(2.f*sp*sp) - 0.5f;
      }
    }
    if (jb == 0) kl_buf[t*256 + b] = kl;
  }
  __syncthreads();
  // z @ Wz (K=32)
  {
    const u16* zr = wz + (long)(j0 + wv*16 + r16)*32 + kg*8;
    short8 bR = *(const short8*)(zr);
    short8 bZ = *(const short8*)(zr + (long)768*32);
    short8 bN = *(const short8*)(zr + (long)1536*32);
    #pragma unroll
    for (int i=0;i<2;i++){
      short8 a = *(const short8*)(zS + (i*16 + r16)*40 + kg*8);
      aR[i]=mfma16(a,bR,aR[i]); aZ[i]=mfma16(a,bZ,aZ[i]); aN[i]=mfma16(a,bN,aN[i]);
    }
  }
  // GRU0 nonlinearity -> h0'
  int col = j0 + wv*16 + r16;
  float bgr = beta_g[col], bgz = beta_g[768+col], bgn = beta_g[1536+col];
  #pragma unroll
  for (int i=0;i<2;i++)
    #pragma unroll
    for (int r=0;r<4;r++){
      int row = m0 + i*16 + kg*4 + r;
      const float* gh = gh0 + (long)row*2304;
      float rr = sigm(aR[i][r] + bgr + gh[col]);
      float zz = sigm(aZ[i][r] + bgz + gh[768+col]);
      float nn = tanhf(aN[i][r] + bgn + rr*gh[1536+col]);
      float hp = bf2f(h0[(long)row*768 + col]);
      h0[(long)row*768 + col] = f2bf((1.f-zz)*nn + zz*hp);
    }
}

// ---------------- per-step stage G: GRU1 -> h1, bp, belief outputs ----------------
__global__ __launch_bounds__(256) void rbn_stepG(
    const u16* __restrict__ h0, const u16* __restrict__ wih1, const float* __restrict__ b_ih1,
    const float* __restrict__ gh1, u16* __restrict__ h1, u16* __restrict__ bp,
    u16* __restrict__ b_seq, float* __restrict__ obel, int t)
{
  __shared__ u16 aS[32*72];
  int mb = blockIdx.x/12, jb = blockIdx.x%12;
  int m0 = mb*32, j0 = jb*64;
  int tid = threadIdx.x;
  int lane = tid & 63, wv = tid >> 6;
  int r16 = lane & 15, kg = lane >> 4;
  f32x4 aR[2], aZ[2], aN[2];
  #pragma unroll
  for (int i=0;i<2;i++){ aR[i]=(f32x4){0,0,0,0}; aZ[i]=(f32x4){0,0,0,0}; aN[i]=(f32x4){0,0,0,0}; }
  const u16* wrp = wih1 + (long)(j0 + wv*16 + r16)*768 + kg*8;
  const u16* wzp = wrp + (long)768*768;
  const u16* wnp = wrp + (long)1536*768;
  for (int kb=0; kb<12; kb++){
    { int r = tid >> 3, c8 = (tid & 7)*8;
      *(short8*)(aS + r*72 + c8) = *(const short8*)(h0 + (long)(m0+r)*768 + kb*64 + c8); }
    __syncthreads();
    #pragma unroll
    for (int kk=0; kk<64; kk+=32){
      int k = kb*64 + kk;
      short8 bR = *(const short8*)(wrp + k);
      short8 bZ = *(const short8*)(wzp + k);
      short8 bN = *(const short8*)(wnp + k);
      #pragma unroll
      for (int i=0;i<2;i++){
        short8 a = *(const short8*)(aS + (i*16 + r16)*72 + kg*8 + kk);
        aR[i]=mfma16(a,bR,aR[i]); aZ[i]=mfma16(a,bZ,aZ[i]); aN[i]=mfma16(a,bN,aN[i]);
      }
    }
    __syncthreads();
  }
  int col = j0 + wv*16 + r16;
  float bir = b_ih1[col], biz = b_ih1[768+col], bin_ = b_ih1[1536+col];
  #pragma unroll
  for (int i=0;i<2;i++)
    #pragma unroll
    for (int r=0;r<4;r++){
      int row = m0 + i*16 + kg*4 + r;
      const float* gh = gh1 + (long)row*2304;
      float rr = sigm(aR[i][r] + bir + gh[col]);
      float zz = sigm(aZ[i][r] + biz + gh[768+col]);
      float nn = tanhf(aN[i][r] + bin_ + rr*gh[1536+col]);
      float hp = bf2f(h1[(long)row*768 + col]);
      float hn = (1.f-zz)*nn + zz*hp;
      h1[(long)row*768 + col] = f2bf(hn);
      float bt = fmaxf(hn, 0.f);
      bp[(long)row*768 + col] = f2bf(bt);
      long o = ((long)row*63 + t)*768 + col;
      b_seq[o] = f2bf(bt);
      obel[o] = bt;
    }
}

// ---------------- decoder ----------------
__global__ __launch_bounds__(256) void rbn_dec1(const u16* __restrict__ b_seq, const u16* __restrict__ z_seq,
    const u16* __restrict__ wd1, const float* __restrict__ b_d1, u16* __restrict__ hdec)
{
  __shared__ u16 aS[64*72];
  int mb = blockIdx.x/12, nb = blockIdx.x%12;
  int lane = threadIdx.x & 63, wv = threadIdx.x >> 6;
  int r16 = lane & 15, kg = lane >> 4;
  f32x4 acc[4]; for (int i=0;i<4;i++) acc[i] = (f32x4){0.f,0.f,0.f,0.f};
  int n0 = nb*64 + wv*16;
  mm64s(aS, b_seq + (long)mb*64*768, 768, wd1 + (long)n0*800, 800, 768, acc);
  { // z part, K=32, direct
    const u16* wp = wd1 + (long)(n0 + r16)*800 + 768 + kg*8;
    short8 b = *(const short8*)wp;
    #pragma unroll
    for (int i=0;i<4;i++){
      long row = (long)mb*64 + i*16 + r16;
      short8 a = *(const short8*)(z_seq + row*32 + kg*8);
      acc[i] = mfma16(a, b, acc[i]);
    }
  }
  int col = n0 + r16; float bv = b_d1[col];
  #pragma unroll
  for (int i=0;i<4;i++)
    #pragma unroll
    for (int r=0;r<4;r++){
      long row = (long)mb*64 + i*16 + kg*4 + r;
      float x = acc[i][r] + bv;
      float g = 0.5f*x*(1.f + erff(x*0.70710678118f));
      hdec[row*768 + col] = f2bf(g);
    }
}
__global__ __launch_bounds__(256) void rbn_pred(const u16* __restrict__ hdec, const u16* __restrict__ wd2,
    const float* __restrict__ b_d2, const float* __restrict__ visual,
    float* __restrict__ out_pred, float* __restrict__ racc)
{
  __shared__ u16 aS[64*72];
  int mb = blockIdx.x/12, nb = blockIdx.x%12;
  int lane = threadIdx.x & 63, wv = threadIdx.x >> 6;
  int r16 = lane & 15, kg = lane >> 4;
  f32x4 acc[4]; for (int i=0;i<4;i++) acc[i] = (f32x4){0.f,0.f,0.f,0.f};
  int n0 = nb*64 + wv*16;
  mm64s(aS, hdec + (long)mb*64*768, 768, wd2 + (long)n0*768, 768, 768, acc);
  int col = n0 + r16; float bv = b_d2[col];
  float loc = 0.f;
  #pragma unroll
  for (int i=0;i<4;i++)
    #pragma unroll
    for (int r=0;r<4;r++){
      long row = (long)mb*64 + i*16 + kg*4 + r;
      int b = (int)(row/63), tt = (int)(row%63);
      float v = acc[i][r] + bv;
      out_pred[row*768 + col] = v;
      float d = v - visual[((long)b*64 + tt + 1)*768 + col];
      loc += d*d;
    }
  __shared__ float red[256];
  red[threadIdx.x] = loc; __syncthreads();
  for (int w=128; w; w>>=1){ if (threadIdx.x<w) red[threadIdx.x]+=red[threadIdx.x+w]; __syncthreads(); }
  if (threadIdx.x==0) atomicAdd(racc, red[0]);
}

// ---------------- NCE: per-b Gram with online LSE ----------------
__global__ __launch_bounds__(256) void rbn_nce(const u16* __restrict__ f_seq, float* __restrict__ nce_p){
  int b = blockIdx.x;
  const u16* F = f_seq + (long)b*63*768;
  __shared__ float inorm[64];
  __shared__ u16 sb[16*776];
  __shared__ u16 tbl[16*776];
  __shared__ float red[256];
  int tid = threadIdx.x;
  {
    int srow = tid >> 2, q4 = tid & 3;
    float p = 0.f;
    if (srow < 63){ const u16* fr = F + (long)srow*768 + q4*192; for (int d=0; d<192; ++d){ float v=bf2f(fr[d]); p += v*v; } }
    red[tid] = p; __syncthreads();
    if (tid < 63){
      float n2 = red[tid*4]+red[tid*4+1]+red[tid*4+2]+red[tid*4+3];
      inorm[tid] = 1.f/fmaxf(sqrtf(n2), 1e-12f);
    }
    __syncthreads();
  }
  float acc = 0.f;
  int ti_ = tid >> 4, tj = tid & 15;
  for (int sbk=0; sbk<4; ++sbk){
    int sbase = sbk*16;
    __syncthreads();
    for (int idx=tid; idx<16*768; idx+=256){
      int rr = idx/768, dd = idx%768; int sg = sbase + rr;
      sb[rr*776+dd] = (sg<63) ? f2bf(bf2f(F[(long)sg*768 + dd]) * inorm[sg]) : (u16)0;
    }
    float m_run = -1e30f, s_run = 0.f, tv = 0.f;
    for (int tbk=0; tbk<4; ++tbk){
      int tbase = tbk*16;
      __syncthreads();
      for (int idx=tid; idx<16*768; idx+=256){
        int rr = idx/768, dd = idx%768; int tg = tbase + rr;
        tbl[rr*776+dd] = (tg<63) ? f2bf(bf2f(F[(long)tg*768 + dd]) * inorm[tg]) : (u16)0;
      }
      __syncthreads();
      float dot = 0.f;
      const u16* sr = sb + ti_*776; const u16* tr = tbl + tj*776;
      for (int d=0; d<768; ++d) dot += bf2f(sr[d])*bf2f(tr[d]);
      dot *= 10.f;
      int tg = tbase + tj;
      float dval = (tg < 63) ? dot : -1e30f;
      float bm = dval;
      for (int off=1; off<16; off<<=1) bm = fmaxf(bm, __shfl_xor(bm, off));
      float mn = fmaxf(m_run, bm);
      float ex = (tg < 63) ? __expf(dval - mn) : 0.f;
      for (int off=1; off<16; off<<=1) ex += __shfl_xor(ex, off);
      s_run = s_run*__expf(m_run - mn) + ex;
      m_run = mn;
      int sg = sbase + ti_;
      float tc = (tg == sg+1) ? dot : 0.f;
      for (int off=1; off<16; off<<=1) tc += __shfl_xor(tc, off);
      tv += tc;
    }
    int sg = sbase + ti_;
    if (tj == 0 && sg < 62) acc += tv - (m_run + logf(s_run));
  }
  __syncthreads();
  red[tid] = acc; __syncthreads();
  for (int w=128; w; w>>=1){ if (tid<w) red[tid]+=red[tid+w]; __syncthreads(); }
  if (tid==0) nce_p[b] = red[0];
}

__global__ __launch_bounds__(256) void rbn_final(const float* __restrict__ kl_buf,
    const float* __restrict__ nce_p, const float* __restrict__ racc, float* __restrict__ out)
{
  __shared__ float red[256]; __shared__ float klv;
  int tid = threadIdx.x;
  float s = 0.f;
  for (int i=tid; i<16128; i+=256) s += kl_buf[i];
  red[tid] = s; __syncthreads();
  for (int w=128; w; w>>=1){ if (tid<w) red[tid]+=red[tid+w]; __syncthreads(); }
  if (tid==0) klv = red[0]/(63.f*256.f);
  __syncthreads();
  red[tid] = nce_p[tid]; __syncthreads();
  for (int w=128; w; w>>=1){ if (tid<w) red[tid]+=red[tid+w]; __syncthreads(); }
  if (tid==0){
    float nce = -red[0]/(256.f*62.f);
    float recon = racc[0]/(256.f*63.f*768.f);
    out[0] = recon + klv + nce; out[1] = recon; out[2] = klv; out[3] = nce;
  }
}

// =====================================================================
extern "C" void kernel_launch(void* const* d_in, const int* in_sizes, int n_in,
                              void* d_out, int out_size, void* d_ws, size_t ws_size,
                              hipStream_t stream)
{
  const float* visual = (const float*)d_in[0];
  const float* state  = (const float*)d_in[1];
  const float* eps    = (const float*)d_in[2];
  const float* w_vis = (const float*)d_in[3];  const float* b_vis = (const float*)d_in[4];
  const float* w_st  = (const float*)d_in[5];  const float* b_st  = (const float*)d_in[6];
  const float* w_bt  = (const float*)d_in[7];  const float* b_bt  = (const float*)d_in[8];
  const float* w_q   = (const float*)d_in[9];  const float* b_q   = (const float*)d_in[10];
  const float* w_k   = (const float*)d_in[11]; const float* b_k   = (const float*)d_in[12];
  const float* w_v   = (const float*)d_in[13]; const float* b_v   = (const float*)d_in[14];
  const float* w_o   = (const float*)d_in[15]; const float* b_o   = (const float*)d_in[16];
  const float* w_pr  = (const float*)d_in[17]; const float* b_pr  = (const float*)d_in[18];
  const float* w_po  = (const float*)d_in[19]; const float* b_po  = (const float*)d_in[20];
  const float* w_ih0 = (const float*)d_in[21]; const float* w_hh0 = (const float*)d_in[22];
  const float* b_ih0 = (const float*)d_in[23]; const float* b_hh0 = (const float*)d_in[24];
  const float* w_ih1 = (const float*)d_in[25]; const float* w_hh1 = (const float*)d_in[26];
  const float* b_ih1 = (const float*)d_in[27]; const float* b_hh1 = (const float*)d_in[28];
  const float* w_d1  = (const float*)d_in[29]; const float* b_d1  = (const float*)d_in[30];
  const float* w_d2  = (const float*)d_in[31]; const float* b_d2  = (const float*)d_in[32];

  float* out = (float*)d_out;
  float* out_pred   = out + 4;
  float* out_belief = out + 4 + 12386304;

  // ---- carve workspace ----
  char* p = (char*)d_ws;
  auto alloc = [&](size_t bytes)->char*{ char* r = p; p += (bytes + 255) & ~(size_t)255; return r; };
  auto aU = [&](size_t elems)->u16*  { return (u16*)alloc(elems*2); };
  auto aF = [&](size_t elems)->float*{ return (float*)alloc(elems*4); };

  u16* wb_q   = aU(589824);  u16* wb_k   = aU(589824);  u16* wb_v   = aU(589824);
  u16* wb_o   = aU(589824);  u16* wb_po  = aU(98304);   u16* wb_pr  = aU(49152);
  u16* wb_hh0 = aU(1769472); u16* wb_hh1 = aU(1769472);
  u16* wb_ih1 = aU(1769472); u16* wb_ih0f = aU(1769472); u16* wz_ex = aU(73728);
  u16* wb_d1  = aU(614400);  u16* wb_d2  = aU(589824);
  u16* wb_vis_t = aU(589824); u16* wb_bt_t = aU(589824); u16* wb_o_t = aU(589824);
  u16* Wc_vq  = aU(589824);  u16* Wc_vk  = aU(589824);  u16* Wc_vv  = aU(589824);
  u16* Wc_bkv = aU(1179648); u16* Wc_c   = aU(49152);   u16* Wc_f   = aU(1769472);
  u16* vis_tb = aU(12386304);            // reused as hdec in post phase
  u16* q2     = aU(12386304);
  u16* v1     = aU(12386304);
  u16* v2     = aU(12386304);
  u16* ctx_seq= aU(12386304);
  u16* f_seq  = aU(12386304);
  u16* b_seq  = aU(12386304);
  u16* z_seq  = aU(516096);
  u16* kv0    = aU(393216);
  u16* bp     = aU(196608);
  u16* h0     = aU(196608);
  u16* h1     = aU(196608);
  u16* hdec   = vis_tb;

  float* W_sk = aF(9216);  float* W_sv = aF(9216);
  float* beta_vq = aF(768); float* beta_vk = aF(768); float* beta_vv = aF(768);
  float* beta_bkv = aF(1536);
  float* beta_sk = aF(768); float* beta_sv = aF(768);
  float* beta_c  = aF(64);  float* beta_g  = aF(2304);
  float* s12   = aF(387072);
  float* gh0   = aF(589824); float* gh1 = aF(589824);
  float* pr    = aF(16384);  float* po_b = aF(16384);
  float* kl_buf = aF(16128);
  float* nce_p  = aF(256);
  float* recon_acc = aF(8);
  (void)ws_size; (void)out_size; (void)n_in; (void)in_sizes;

  // ---- pre-pass ----
  rbn_zero<<<768,256,0,stream>>>(bp, h0, h1, recon_acc);

  auto CVT = [&](const float* in, u16* o, int n){ rbn_cvt8<<<(n/8+255)/256,256,0,stream>>>(in,o,n/8); };
  CVT(w_q, wb_q, 589824);   CVT(w_k, wb_k, 589824);   CVT(w_v, wb_v, 589824);
  CVT(w_o, wb_o, 589824);   CVT(w_po, wb_po, 98304);  CVT(w_pr, wb_pr, 49152);
  CVT(w_hh0, wb_hh0, 1769472); CVT(w_hh1, wb_hh1, 1769472); CVT(w_ih1, wb_ih1, 1769472);
  CVT(w_d1, wb_d1, 614400); CVT(w_d2, wb_d2, 589824);
  rbn_cvt_ih0f<<<864,256,0,stream>>>(w_ih0, wb_ih0f);
  rbn_cvt_wz<<<36,256,0,stream>>>(w_ih0, wz_ex);
  rbn_cvtT<<<2304,256,0,stream>>>(w_vis, wb_vis_t, 768, 768);
  rbn_cvtT<<<2304,256,0,stream>>>(w_bt,  wb_bt_t,  768, 768);
  rbn_cvtT<<<2304,256,0,stream>>>(w_o,   wb_o_t,   768, 768);

  rbn_wsmall<<<768,64,0,stream>>>(w_k, w_st, W_sk);
  rbn_wsmall<<<768,64,0,stream>>>(w_v, w_st, W_sv);

  rbn_matvec<<<768,256,0,stream>>>(w_q, 768, 768, b_vis, b_q, beta_vq);
  rbn_matvec<<<768,256,0,stream>>>(w_k, 768, 768, b_vis, b_k, beta_vk);
  rbn_matvec<<<768,256,0,stream>>>(w_v, 768, 768, b_vis, b_v, beta_vv);
  rbn_matvec<<<768,256,0,stream>>>(w_k, 768, 768, b_bt, b_k, beta_bkv);
  rbn_matvec<<<768,256,0,stream>>>(w_v, 768, 768, b_bt, b_v, beta_bkv + 768);
  rbn_matvec<<<768,256,0,stream>>>(w_k, 768, 768, b_st, b_k, beta_sk);
  rbn_matvec<<<768,256,0,stream>>>(w_v, 768, 768, b_st, b_v, beta_sv);
  rbn_matvec<<<64,256,0,stream>>>(w_po + 768, 1536, 768, b_o, b_po, beta_c);
  rbn_matvec<<<2304,256,0,stream>>>(w_ih0, 800, 768, b_o, b_ih0, beta_g);

  // combined weights (bf16 GEMMs)
  rbn_gemm<1><<<144,256,0,stream>>>(wb_q, 768, wb_vis_t, 768, 768, nullptr, Wc_vq, 768, 12);
  rbn_gemm<1><<<144,256,0,stream>>>(wb_k, 768, wb_vis_t, 768, 768, nullptr, Wc_vk, 768, 12);
  rbn_gemm<1><<<144,256,0,stream>>>(wb_v, 768, wb_vis_t, 768, 768, nullptr, Wc_vv, 768, 12);
  rbn_gemm<1><<<144,256,0,stream>>>(wb_k, 768, wb_bt_t, 768, 768, nullptr, Wc_bkv, 768, 12);
  rbn_gemm<1><<<144,256,0,stream>>>(wb_v, 768, wb_bt_t, 768, 768, nullptr, Wc_bkv + (long)768*768, 768, 12);
  rbn_gemm<1><<<12,256,0,stream>>>(wb_po + 768, 1536, wb_o_t, 768, 768, nullptr, Wc_c, 768, 12);
  rbn_gemm<1><<<432,256,0,stream>>>(wb_ih0f, 768, wb_o_t, 768, 768, nullptr, Wc_f, 768, 12);

  // projections for all steps
  rbn_cvt_vis<<<16128,256,0,stream>>>(visual, vis_tb);
  rbn_gemm<1><<<3024,256,0,stream>>>(vis_tb, 768, Wc_vq, 768, 768, beta_vq, q2, 768, 12);
  rbn_gemm<1><<<3024,256,0,stream>>>(vis_tb, 768, Wc_vv, 768, 768, beta_vv, v2, 768, 12);
  rbn_v1<<<48384,256,0,stream>>>(state, W_sv, beta_sv, v1);
  rbn_s12<<<3024,256,0,stream>>>(vis_tb, Wc_vk, beta_vk, W_sk, beta_sk, state, q2, s12);

  // ---- sequential scan: 3 launches/step ----
  for (int t=0; t<63; ++t){
    rbn_stepA<<<392,256,0,stream>>>(bp, h0, h1, Wc_bkv, beta_bkv, wb_hh0, b_hh0,
                                    wb_hh1, b_hh1, wb_pr, b_pr, wb_po,
                                    kv0, gh0, gh1, pr, po_b);
    rbn_stepC<<<96,256,0,stream>>>(q2, kv0, v1, v2, s12, Wc_f, beta_g, Wc_c, beta_c,
                                   wz_ex, po_b, pr, eps, gh0, h0, ctx_seq, z_seq, kl_buf, t);
    rbn_stepG<<<96,256,0,stream>>>(h0, wb_ih1, b_ih1, gh1, h1, bp, b_seq, out_belief, t);
  }

  // ---- post ----
  rbn_gemm<2><<<3024,256,0,stream>>>(ctx_seq, 768, wb_o, 768, 768, b_o, f_seq, 768, 12);
  rbn_dec1<<<3024,256,0,stream>>>(b_seq, z_seq, wb_d1, b_d1, hdec);
  rbn_pred<<<3024,256,0,stream>>>(hdec, wb_d2, b_d2, visual, out_pred, recon_acc);
  rbn_nce<<<256,256,0,stream>>>(f_seq, nce_p);
  rbn_final<<<1,256,0,stream>>>(kl_buf, nce_p, recon_acc, out);
}